// Round 18
// baseline (246.224 us; speedup 1.0000x reference)
//
#include <hip/hip_runtime.h>
#include <stdint.h>

#define K_DIM 4096
#define N_DIM 11008
#define WORDS_N 1376          // N_DIM / 8 packed words
#define NDEQ (172 * 64)       // dequant tiles: (WORDS_N/8) x (K_DIM/64)
#define BM 128
#define BN 256
#define BK 64
#define ASTR 72               // fused-fallback As stride
#define WSTR 68               // Wq stride (ints)

typedef _Float16 f16x2 __attribute__((ext_vector_type(2)));
typedef _Float16 f16x8 __attribute__((ext_vector_type(8)));
typedef float    f32x4 __attribute__((ext_vector_type(4)));
typedef float    f32x8 __attribute__((ext_vector_type(8)));
typedef int      int4v __attribute__((ext_vector_type(4)));
typedef int      int2v __attribute__((ext_vector_type(2)));
typedef unsigned short ushort;
typedef unsigned int u32;

__device__ __forceinline__ f16x2 dq2(int wa, int wb, int shf, f16x2 s2, f16x2 c2) {
    u32 t0 = ((u32)wa >> shf) & 0xFu;
    u32 t1 = ((u32)wb >> shf) & 0xFu;
    u32 h  = 0x64006400u | t0 | (t1 << 16);
    f16x2 q = __builtin_bit_cast(f16x2, h);
    q = q - (f16x2)((_Float16)1024.0f);
    return q * s2 + c2;
}

__device__ __forceinline__ void gload16(const void* g, void* l) {
    __builtin_amdgcn_global_load_lds(
        (const __attribute__((address_space(1))) unsigned int*)g,
        (__attribute__((address_space(3))) unsigned int*)l, 16, 0, 0);
}

// ---- standalone cvt (fallback path only) ----
__global__ __launch_bounds__(256)
void cvt_x_kernel(const float* __restrict__ x, ushort* __restrict__ xf, int n8) {
    for (int i = blockIdx.x * 256 + threadIdx.x; i < n8; i += gridDim.x * 256) {
        f32x4 a = *(const f32x4*)(x + (size_t)i * 8);
        f32x4 b = *(const f32x4*)(x + (size_t)i * 8 + 4);
        int4v o;
        o[0] = __builtin_bit_cast(int, __builtin_amdgcn_cvt_pkrtz(a[0], a[1]));
        o[1] = __builtin_bit_cast(int, __builtin_amdgcn_cvt_pkrtz(a[2], a[3]));
        o[2] = __builtin_bit_cast(int, __builtin_amdgcn_cvt_pkrtz(b[0], b[1]));
        o[3] = __builtin_bit_cast(int, __builtin_amdgcn_cvt_pkrtz(b[2], b[3]));
        *(int4v*)(xf + (size_t)i * 8) = o;
    }
}

// ---- fused pre-pass: blocks [0, NDEQ) dequant qweight -> Wf (fragment order);
//      blocks [NDEQ, grid) grid-stride cvt x f32 -> fp16. The two phases are
//      data-independent; fusing one launch runs their memory streams
//      concurrently instead of serializing on the stream. ----
__global__ __launch_bounds__(256)
void prepass_kernel(const float* __restrict__ x, ushort* __restrict__ xf, int n8,
                    const int* __restrict__ qw, const int* __restrict__ qz,
                    const float* __restrict__ sc, f16x8* __restrict__ Wf)
{
    __shared__ __align__(16) int Wq[8 * WSTR];
    const int bid = blockIdx.x;
    const int t   = threadIdx.x;

    if (bid < NDEQ) {
        // ---- dequant tile (body identical to verified dequant_w_kernel) ----
        const int bxd = bid % 172;
        const int byd = bid / 172;
        const int w0 = bxd * 8;
        const int n0 = bxd * 64;
        const int k0 = byd * 64;
        {
            const int k  = t >> 2;
            const int wp = (t & 3) * 2;
            const int2v v = *(const int2v*)(qw + (size_t)(k0 + k) * WORDS_N + w0 + wp);
            Wq[(wp + 0) * WSTR + k] = v[0];
            Wq[(wp + 1) * WSTR + k] = v[1];
        }
        __syncthreads();

        const int n   = t & 63;
        const int oc0 = t >> 6;
        const int w   = n >> 3;
        const int j   = n & 7;
        const int shf = ((j & 1) << 4) + ((j >> 1) << 2);   // AWQ interleave
        const int g   = k0 >> 7;

        const int   nn = n0 + n;
        const float s  = sc[(size_t)g * N_DIM + nn];
        const int   zq = (qz[(size_t)g * WORDS_N + w0 + w] >> shf) & 0xF;
        const float nz = -(float)zq * s;

        #pragma unroll
        for (int oo = 0; oo < 2; ++oo) {
            const int oc = oc0 + oo * 4;
            const int4v lo = *(const int4v*)&Wq[w * WSTR + oc * 8];
            const int4v hi = *(const int4v*)&Wq[w * WSTR + oc * 8 + 4];
            f16x8 h;
            #pragma unroll
            for (int r = 0; r < 4; ++r)
                h[r] = (_Float16)((float)((lo[r] >> shf) & 0xF) * s + nz);
            #pragma unroll
            for (int r = 0; r < 4; ++r)
                h[4 + r] = (_Float16)((float)((hi[r] >> shf) & 0xF) * s + nz);
            const size_t kidx = (size_t)((k0 >> 3) + oc);
            Wf[((size_t)(nn >> 4) * 512 + kidx) * 16 + (nn & 15)] = h;
        }
    } else {
        // ---- cvt x -> fp16 (grid-stride over the tail blocks) ----
        const int nblk = gridDim.x - NDEQ;
        for (int i = (bid - NDEQ) * 256 + t; i < n8; i += nblk * 256) {
            f32x4 a = *(const f32x4*)(x + (size_t)i * 8);
            f32x4 b = *(const f32x4*)(x + (size_t)i * 8 + 4);
            int4v o;
            o[0] = __builtin_bit_cast(int, __builtin_amdgcn_cvt_pkrtz(a[0], a[1]));
            o[1] = __builtin_bit_cast(int, __builtin_amdgcn_cvt_pkrtz(a[2], a[3]));
            o[2] = __builtin_bit_cast(int, __builtin_amdgcn_cvt_pkrtz(b[0], b[1]));
            o[3] = __builtin_bit_cast(int, __builtin_amdgcn_cvt_pkrtz(b[2], b[3]));
            *(int4v*)(xf + (size_t)i * 8) = o;
        }
    }
}

// ---- main GEMM (best verified, rounds 14/17): 128M x 256N block, 4 waves each
//      owning 128x64 (acc[8][4]). Tri-buffered A (gload_lds+swizzle), ONE
//      barrier + counted vmcnt(12) per K-tile, B double-buffered in regs from
//      fragment-ordered Wf. 2 blocks/CU for cross-block latency cover. ----
__global__ __launch_bounds__(256, 2)
void awq_gemm_pipe(const ushort* __restrict__ x16,
                   const f16x8* __restrict__ Wf,
                   const float* __restrict__ bias,
                   float* __restrict__ out,
                   int M, int nwg)
{
    __shared__ __align__(16) _Float16 As[3][128 * 64];  // 3 x 16 KB, A only

    const int tid  = threadIdx.x;
    const int lane = tid & 63;
    const int wid  = tid >> 6;

    // XCD swizzle: nwg divisible by 8; consecutive logical g share bx (B panel).
    const int hh  = blockIdx.x;
    const int g   = (hh & 7) * (nwg >> 3) + (hh >> 3);
    const int bx  = g >> 4;          // N tile (0..42)
    const int by  = g & 15;          // M tile (0..15)
    const int bn0 = bx * 256;
    const int bm0 = by * 128;

    const int wn0 = wid * 64;        // wave owns all 128 rows x 64 distinct cols

    // A staging: linear LDS dest, pre-swizzled global slot (proven round 10)
    const int srow = lane >> 3;
    const int slot = (lane & 7) ^ srow;
    const ushort* aSrc = x16 + (size_t)(bm0 + wid * 32 + srow) * K_DIM + slot * 8;

#define STAGE_A(BUFP, K0)                                                       \
    {                                                                           \
        _Pragma("unroll")                                                       \
        for (int jj = 0; jj < 4; ++jj)                                          \
            gload16(aSrc + (size_t)(K0) + jj * 8 * K_DIM,                       \
                    (BUFP) + (wid * 32 + jj * 8) * 64);                         \
    }

    // B fragment bases: unit idx = ntile*8192 + T*128 + ks*64 + lane
    size_t nb[4];
    #pragma unroll
    for (int n = 0; n < 4; ++n)
        nb[n] = ((size_t)((bn0 + wn0) >> 4) + n) * 8192 + lane;

    f32x4 acc[8][4];
    #pragma unroll
    for (int i = 0; i < 8; ++i)
        #pragma unroll
        for (int j = 0; j < 4; ++j)
            acc[i][j] = (f32x4){0.f, 0.f, 0.f, 0.f};

    f16x8 BR0[8], BR1[8];
    const int NT = K_DIM / 64;  // 64

#define LOADB(DST, T)                                                           \
    {                                                                           \
        const size_t koff = (size_t)(T) * 128;                                  \
        _Pragma("unroll")                                                       \
        for (int jj = 0; jj < 8; ++jj)                                          \
            DST[jj] = Wf[nb[jj & 3] + koff + (size_t)(jj >> 2) * 64];           \
    }

    const int rd_sw = (lane & 7) << 4;
    const int rrow  = lane & 15;

    // prologue: A0 -> buf0, B0 -> regs, A1 -> buf1 (issue order = vmcnt order)
    STAGE_A(&As[0][0], 0);
    LOADB(BR0, 0);
    STAGE_A(&As[1][0], 64);

    int rd = 0;   // buffer holding tile T (cycles 0,1,2)

    // ONE barrier per K-tile. STAGE at end of iter T writes buf[(rd+2)%3],
    // last read in iter T-1 (its readers passed this iter's top barrier).
    // In flight at top of T: B(T)8 + A(T+1)4 newer than A(T) -> vmcnt(12).
#define ITER(T, BRD, BWR)                                                          \
    {                                                                              \
        asm volatile("s_waitcnt vmcnt(12)" ::: "memory");                          \
        __builtin_amdgcn_sched_barrier(0);                                         \
        __builtin_amdgcn_s_barrier();                                              \
        __builtin_amdgcn_sched_barrier(0);                                         \
        { const int tn = ((T) + 1 < NT) ? (T) + 1 : NT - 1; LOADB(BWR, tn); }      \
        __builtin_amdgcn_sched_barrier(0);                                         \
        const char* aB = (const char*)&As[rd][0];                                  \
        _Pragma("unroll")                                                          \
        for (int ks = 0; ks < 2; ++ks) {                                           \
            const int kb = ks * 64 + ((lane >> 4) << 4);                           \
            __builtin_amdgcn_s_setprio(1);                                         \
            _Pragma("unroll")                                                      \
            for (int m = 0; m < 8; ++m) {                                          \
                f16x8 af = *(const f16x8*)(aB + (m * 16 + rrow) * 128 + (kb ^ rd_sw)); \
                _Pragma("unroll")                                                  \
                for (int n = 0; n < 4; ++n)                                        \
                    acc[m][n] = __builtin_amdgcn_mfma_f32_16x16x32_f16(            \
                        af, BRD[ks * 4 + n], acc[m][n], 0, 0, 0);                  \
            }                                                                      \
            __builtin_amdgcn_s_setprio(0);                                         \
        }                                                                          \
        {                                                                          \
            const int stg = (rd >= 1) ? rd - 1 : 2;        /* (rd+2)%3 */          \
            const int t2  = ((T) + 2 < NT) ? (T) + 2 : NT - 1;                     \
            STAGE_A(&As[stg][0], t2 * 64);                                         \
        }                                                                          \
        rd = (rd < 2) ? rd + 1 : 0;                                                \
    }

    for (int t = 0; t < NT; t += 2) {
        ITER(t,     BR0, BR1);
        ITER(t + 1, BR1, BR0);
    }
#undef ITER
#undef LOADB
#undef STAGE_A

    // epilogue: C/D col=lane&15, row=(lane>>4)*4+r (m89-verified)
    #pragma unroll
    for (int n = 0; n < 4; ++n) {
        const int col = bn0 + wn0 + n * 16 + (lane & 15);
        const float b_f = bias[col];
        #pragma unroll
        for (int m = 0; m < 8; ++m) {
            const int row_base = bm0 + m * 16 + ((lane >> 4) << 2);
            #pragma unroll
            for (int r = 0; r < 4; ++r) {
                const int row = row_base + r;
                if (row < M)
                    out[(size_t)row * N_DIM + col] = acc[m][n][r] + b_f;
            }
        }
    }
}

// ---- fallback: fused kernel (proven rounds 6-8) ----
template <bool XF16>
__global__ __launch_bounds__(256, 2)
void awq_gemm_fused(const void* __restrict__ xin,
                    const int* __restrict__ qw,
                    const int* __restrict__ qz,
                    const float* __restrict__ sc,
                    const float* __restrict__ bias,
                    float* __restrict__ out,
                    int M)
{
    __shared__ __align__(16) _Float16 Asf[BM * ASTR];
    __shared__ __align__(16) int Wq[32 * WSTR];

    const int tid  = threadIdx.x;
    const int lane = tid & 63;
    const int wid  = tid >> 6;
    const int bn0 = blockIdx.x * BN;
    const int bm0 = blockIdx.y * BM;
    const int w0  = bn0 >> 3;
    const int wn0 = wid * 64;
    const int a_row = tid >> 3;
    const int a_col = (tid & 7) * 8;
    const int b_krow = tid >> 2;
    const int b_wg   = (tid & 3) * 4;

    int n_loc[4], w_loc[4], shf[4];
    #pragma unroll
    for (int bn = 0; bn < 4; ++bn) {
        n_loc[bn] = wn0 + bn * 16 + (lane & 15);
        w_loc[bn] = n_loc[bn] >> 3;
        int j = n_loc[bn] & 7;
        shf[bn] = ((j & 1) << 4) + ((j >> 1) << 2);
    }
    f16x2 s2[4], c2[4];
    f32x4 acc[8][4];
    #pragma unroll
    for (int i = 0; i < 8; ++i)
        #pragma unroll
        for (int j = 0; j < 4; ++j)
            acc[i][j] = (f32x4){0.f, 0.f, 0.f, 0.f};
    int4v aReg16[4];
    f32x8 aReg32[4];
    int4v bReg[2];
    const ushort* x16 = (const ushort*)xin;
    const float*  x32 = (const float*)xin;

#define LOAD_TILE(K0)                                                                  \
    {                                                                                  \
        _Pragma("unroll")                                                              \
        for (int i = 0; i < 4; ++i) {                                                  \
            int row = bm0 + a_row + i * 32;                                            \
            if constexpr (XF16) {                                                      \
                if (row < M)                                                           \
                    aReg16[i] = *(const int4v*)(x16 + (size_t)row * K_DIM + (K0) + a_col); \
                else aReg16[i] = (int4v){0, 0, 0, 0};                                  \
            } else {                                                                   \
                if (row < M)                                                           \
                    aReg32[i] = *(const f32x8*)(x32 + (size_t)row * K_DIM + (K0) + a_col); \
                else aReg32[i] = (f32x8){0.f,0.f,0.f,0.f,0.f,0.f,0.f,0.f};             \
            }                                                                          \
        }                                                                              \
        bReg[0] = *(const int4v*)(qw + (size_t)((K0) + b_krow) * WORDS_N + w0 + b_wg);      \
        bReg[1] = *(const int4v*)(qw + (size_t)((K0) + b_krow) * WORDS_N + w0 + b_wg + 16); \
    }

    LOAD_TILE(0);
    const int NT = K_DIM / BK;
    for (int t = 0; t < NT; ++t) {
        const int k0 = t * BK;
        __syncthreads();
        #pragma unroll
        for (int i = 0; i < 4; ++i) {
            if constexpr (XF16) {
                *(int4v*)&Asf[(a_row + i * 32) * ASTR + a_col] = aReg16[i];
            } else {
                f16x8 hh2;
                #pragma unroll
                for (int r = 0; r < 4; ++r) {
                    f16x2 p = __builtin_bit_cast(f16x2,
                        __builtin_amdgcn_cvt_pkrtz(aReg32[i][2*r], aReg32[i][2*r+1]));
                    hh2[2*r] = p[0]; hh2[2*r+1] = p[1];
                }
                *(f16x8*)&Asf[(a_row + i * 32) * ASTR + a_col] = hh2;
            }
        }
        #pragma unroll
        for (int c = 0; c < 4; ++c) {
            Wq[(b_wg + c) * WSTR + b_krow]      = bReg[0][c];
            Wq[(b_wg + 16 + c) * WSTR + b_krow] = bReg[1][c];
        }
        __syncthreads();
        if (t + 1 < NT) LOAD_TILE(k0 + BK);
        if ((t & 1) == 0) {
            const int gg = k0 >> 7;
            #pragma unroll
            for (int bn = 0; bn < 4; ++bn) {
                float s = sc[(size_t)gg * N_DIM + bn0 + n_loc[bn]];
                int zq  = (qz[(size_t)gg * WORDS_N + w0 + w_loc[bn]] >> shf[bn]) & 0xF;
                _Float16 sh = (_Float16)s;
                _Float16 nz = (_Float16)(-(float)zq * s);
                s2[bn] = (f16x2){sh, sh};
                c2[bn] = (f16x2){nz, nz};
            }
        }
        #pragma unroll
        for (int ks = 0; ks < 2; ++ks) {
            const int kk = ks * 32 + (lane >> 4) * 8;
            f16x8 af[8];
            #pragma unroll
            for (int am = 0; am < 8; ++am)
                af[am] = *(const f16x8*)&Asf[(am * 16 + (lane & 15)) * ASTR + kk];
            #pragma unroll
            for (int bn = 0; bn < 4; ++bn) {
                const int4v lo = *(const int4v*)&Wq[w_loc[bn] * WSTR + kk];
                const int4v hi = *(const int4v*)&Wq[w_loc[bn] * WSTR + kk + 4];
                f16x8 bfr;
                f16x2 p;
                p = dq2(lo[0], lo[1], shf[bn], s2[bn], c2[bn]); bfr[0]=p[0]; bfr[1]=p[1];
                p = dq2(lo[2], lo[3], shf[bn], s2[bn], c2[bn]); bfr[2]=p[0]; bfr[3]=p[1];
                p = dq2(hi[0], hi[1], shf[bn], s2[bn], c2[bn]); bfr[4]=p[0]; bfr[5]=p[1];
                p = dq2(hi[2], hi[3], shf[bn], s2[bn], c2[bn]); bfr[6]=p[0]; bfr[7]=p[1];
                #pragma unroll
                for (int am = 0; am < 8; ++am)
                    acc[am][bn] = __builtin_amdgcn_mfma_f32_16x16x32_f16(
                        af[am], bfr, acc[am][bn], 0, 0, 0);
            }
        }
    }
    #pragma unroll
    for (int bn = 0; bn < 4; ++bn) {
        const int col = bn0 + wn0 + bn * 16 + (lane & 15);
        const float b_f = bias[col];
        #pragma unroll
        for (int am = 0; am < 8; ++am) {
            const int row_base = bm0 + am * 16 + ((lane >> 4) << 2);
            #pragma unroll
            for (int r = 0; r < 4; ++r) {
                const int row = row_base + r;
                if (row < M)
                    out[(size_t)row * N_DIM + col] = acc[am][bn][r] + b_f;
            }
        }
    }
#undef LOAD_TILE
}

extern "C" void kernel_launch(void* const* d_in, const int* in_sizes, int n_in,
                              void* d_out, int out_size, void* d_ws, size_t ws_size,
                              hipStream_t stream) {
    const float* x    = (const float*)d_in[0];
    const int*   qw   = (const int*)d_in[1];
    const int*   qz   = (const int*)d_in[2];
    const float* sc   = (const float*)d_in[3];
    const float* bias = (const float*)d_in[4];
    float*       out  = (float*)d_out;

    const int M = in_sizes[0] / K_DIM;
    const size_t x_bytes = (size_t)M * K_DIM * 2;
    const size_t w_bytes = (size_t)N_DIM * K_DIM * 2;

    if (ws_size >= x_bytes + w_bytes && (M % 128) == 0) {
        ushort* xf = (ushort*)d_ws;
        f16x8*  Wf = (f16x8*)((char*)d_ws + x_bytes);
        prepass_kernel<<<dim3(NDEQ + 2048), dim3(256), 0, stream>>>(
            x, xf, (M * K_DIM) / 8, qw, qz, sc, Wf);
        const int nwg = (N_DIM / 256) * (M / 128);   // 43 x 16 = 688, %8==0
        awq_gemm_pipe<<<dim3(nwg), dim3(256), 0, stream>>>(xf, Wf, bias, out, M, nwg);
    } else if (ws_size >= x_bytes) {
        ushort* xf = (ushort*)d_ws;
        const int mtiles = (M + BM - 1) / BM;
        cvt_x_kernel<<<dim3(2048), dim3(256), 0, stream>>>(x, xf, (M * K_DIM) / 8);
        awq_gemm_fused<true><<<dim3(N_DIM / BN, mtiles), dim3(256), 0, stream>>>(
            xf, qw, qz, sc, bias, out, M);
    } else {
        const int mtiles = (M + BM - 1) / BM;
        awq_gemm_fused<false><<<dim3(N_DIM / BN, mtiles), dim3(256), 0, stream>>>(
            x, qw, qz, sc, bias, out, M);
    }
}

// Round 19
// 242.452 us; speedup vs baseline: 1.0156x; 1.0156x over previous
//
#include <hip/hip_runtime.h>
#include <stdint.h>

#define K_DIM 4096
#define N_DIM 11008
#define WORDS_N 1376          // N_DIM / 8 packed words
#define BM 128
#define BN 256
#define BK 64
#define ASTR 72               // fused-fallback As stride
#define WSTR 68               // Wq stride (ints)

typedef _Float16 f16x2 __attribute__((ext_vector_type(2)));
typedef _Float16 f16x8 __attribute__((ext_vector_type(8)));
typedef float    f32x4 __attribute__((ext_vector_type(4)));
typedef float    f32x8 __attribute__((ext_vector_type(8)));
typedef int      int4v __attribute__((ext_vector_type(4)));
typedef int      int2v __attribute__((ext_vector_type(2)));
typedef unsigned short ushort;
typedef unsigned int u32;

__device__ __forceinline__ f16x2 dq2(int wa, int wb, int shf, f16x2 s2, f16x2 c2) {
    u32 t0 = ((u32)wa >> shf) & 0xFu;
    u32 t1 = ((u32)wb >> shf) & 0xFu;
    u32 h  = 0x64006400u | t0 | (t1 << 16);
    f16x2 q = __builtin_bit_cast(f16x2, h);
    q = q - (f16x2)((_Float16)1024.0f);
    return q * s2 + c2;
}

__device__ __forceinline__ void gload16(const void* g, void* l) {
    __builtin_amdgcn_global_load_lds(
        (const __attribute__((address_space(1))) unsigned int*)g,
        (__attribute__((address_space(3))) unsigned int*)l, 16, 0, 0);
}

// ---- pre-pass 1: x f32 -> fp16 ----
__global__ __launch_bounds__(256)
void cvt_x_kernel(const float* __restrict__ x, ushort* __restrict__ xf, int n8) {
    for (int i = blockIdx.x * 256 + threadIdx.x; i < n8; i += gridDim.x * 256) {
        f32x4 a = *(const f32x4*)(x + (size_t)i * 8);
        f32x4 b = *(const f32x4*)(x + (size_t)i * 8 + 4);
        int4v o;
        o[0] = __builtin_bit_cast(int, __builtin_amdgcn_cvt_pkrtz(a[0], a[1]));
        o[1] = __builtin_bit_cast(int, __builtin_amdgcn_cvt_pkrtz(a[2], a[3]));
        o[2] = __builtin_bit_cast(int, __builtin_amdgcn_cvt_pkrtz(b[0], b[1]));
        o[3] = __builtin_bit_cast(int, __builtin_amdgcn_cvt_pkrtz(b[2], b[3]));
        *(int4v*)(xf + (size_t)i * 8) = o;
    }
}

// ---- pre-pass 2: dequant qweight -> W in MFMA-fragment order ----
// unit = f16x8. unit_idx = (ntile*512 + kidx)*16 + (col&15)
__global__ __launch_bounds__(256)
void dequant_w_kernel(const int* __restrict__ qw,
                      const int* __restrict__ qz,
                      const float* __restrict__ sc,
                      f16x8* __restrict__ Wf)
{
    __shared__ __align__(16) int Wq[8 * WSTR];
    const int t  = threadIdx.x;
    const int w0 = blockIdx.x * 8;
    const int n0 = blockIdx.x * 64;
    const int k0 = blockIdx.y * 64;
    {
        const int k  = t >> 2;
        const int wp = (t & 3) * 2;
        const int2v v = *(const int2v*)(qw + (size_t)(k0 + k) * WORDS_N + w0 + wp);
        Wq[(wp + 0) * WSTR + k] = v[0];
        Wq[(wp + 1) * WSTR + k] = v[1];
    }
    __syncthreads();

    const int n   = t & 63;
    const int oc0 = t >> 6;
    const int w   = n >> 3;
    const int j   = n & 7;
    const int shf = ((j & 1) << 4) + ((j >> 1) << 2);
    const int g   = k0 >> 7;

    const int   nn = n0 + n;
    const float s  = sc[(size_t)g * N_DIM + nn];
    const int   zq = (qz[(size_t)g * WORDS_N + w0 + w] >> shf) & 0xF;
    const float nz = -(float)zq * s;

    #pragma unroll
    for (int oo = 0; oo < 2; ++oo) {
        const int oc = oc0 + oo * 4;
        const int4v lo = *(const int4v*)&Wq[w * WSTR + oc * 8];
        const int4v hi = *(const int4v*)&Wq[w * WSTR + oc * 8 + 4];
        f16x8 h;
        #pragma unroll
        for (int r = 0; r < 4; ++r)
            h[r] = (_Float16)((float)((lo[r] >> shf) & 0xF) * s + nz);
        #pragma unroll
        for (int r = 0; r < 4; ++r)
            h[4 + r] = (_Float16)((float)((hi[r] >> shf) & 0xF) * s + nz);
        const size_t kidx = (size_t)((k0 >> 3) + oc);
        Wf[((size_t)(nn >> 4) * 512 + kidx) * 16 + (nn & 15)] = h;
    }
}

// ---- main GEMM (best verified, rounds 14/17): 128M x 256N block, 4 waves each
//      owning 128x64 (acc[8][4]). Tri-buffered A (gload_lds+swizzle), ONE
//      barrier + counted vmcnt(12) per K-tile, B double-buffered in regs from
//      fragment-ordered Wf. 2 blocks/CU for cross-block latency cover. ----
__global__ __launch_bounds__(256, 2)
void awq_gemm_pipe(const ushort* __restrict__ x16,
                   const f16x8* __restrict__ Wf,
                   const float* __restrict__ bias,
                   float* __restrict__ out,
                   int M, int nwg)
{
    __shared__ __align__(16) _Float16 As[3][128 * 64];  // 3 x 16 KB, A only

    const int tid  = threadIdx.x;
    const int lane = tid & 63;
    const int wid  = tid >> 6;

    // XCD swizzle: nwg divisible by 8; consecutive logical g share bx (B panel).
    const int hh  = blockIdx.x;
    const int g   = (hh & 7) * (nwg >> 3) + (hh >> 3);
    const int bx  = g >> 4;          // N tile (0..42)
    const int by  = g & 15;          // M tile (0..15)
    const int bn0 = bx * 256;
    const int bm0 = by * 128;

    const int wn0 = wid * 64;        // wave owns all 128 rows x 64 distinct cols

    // A staging: linear LDS dest, pre-swizzled global slot (proven round 10)
    const int srow = lane >> 3;
    const int slot = (lane & 7) ^ srow;
    const ushort* aSrc = x16 + (size_t)(bm0 + wid * 32 + srow) * K_DIM + slot * 8;

#define STAGE_A(BUFP, K0)                                                       \
    {                                                                           \
        _Pragma("unroll")                                                       \
        for (int jj = 0; jj < 4; ++jj)                                          \
            gload16(aSrc + (size_t)(K0) + jj * 8 * K_DIM,                       \
                    (BUFP) + (wid * 32 + jj * 8) * 64);                         \
    }

    // B fragment bases: unit idx = ntile*8192 + T*128 + ks*64 + lane
    size_t nb[4];
    #pragma unroll
    for (int n = 0; n < 4; ++n)
        nb[n] = ((size_t)((bn0 + wn0) >> 4) + n) * 8192 + lane;

    f32x4 acc[8][4];
    #pragma unroll
    for (int i = 0; i < 8; ++i)
        #pragma unroll
        for (int j = 0; j < 4; ++j)
            acc[i][j] = (f32x4){0.f, 0.f, 0.f, 0.f};

    f16x8 BR0[8], BR1[8];
    const int NT = K_DIM / 64;  // 64

#define LOADB(DST, T)                                                           \
    {                                                                           \
        const size_t koff = (size_t)(T) * 128;                                  \
        _Pragma("unroll")                                                       \
        for (int jj = 0; jj < 8; ++jj)                                          \
            DST[jj] = Wf[nb[jj & 3] + koff + (size_t)(jj >> 2) * 64];           \
    }

    const int rd_sw = (lane & 7) << 4;
    const int rrow  = lane & 15;

    // prologue: A0 -> buf0, B0 -> regs, A1 -> buf1 (issue order = vmcnt order)
    STAGE_A(&As[0][0], 0);
    LOADB(BR0, 0);
    STAGE_A(&As[1][0], 64);

    int rd = 0;   // buffer holding tile T (cycles 0,1,2)

    // ONE barrier per K-tile. STAGE at end of iter T writes buf[(rd+2)%3],
    // last read in iter T-1 (its readers passed this iter's top barrier).
    // In flight at top of T: B(T)8 + A(T+1)4 newer than A(T) -> vmcnt(12).
#define ITER(T, BRD, BWR)                                                          \
    {                                                                              \
        asm volatile("s_waitcnt vmcnt(12)" ::: "memory");                          \
        __builtin_amdgcn_sched_barrier(0);                                         \
        __builtin_amdgcn_s_barrier();                                              \
        __builtin_amdgcn_sched_barrier(0);                                         \
        { const int tn = ((T) + 1 < NT) ? (T) + 1 : NT - 1; LOADB(BWR, tn); }      \
        __builtin_amdgcn_sched_barrier(0);                                         \
        const char* aB = (const char*)&As[rd][0];                                  \
        _Pragma("unroll")                                                          \
        for (int ks = 0; ks < 2; ++ks) {                                           \
            const int kb = ks * 64 + ((lane >> 4) << 4);                           \
            __builtin_amdgcn_s_setprio(1);                                         \
            _Pragma("unroll")                                                      \
            for (int m = 0; m < 8; ++m) {                                          \
                f16x8 af = *(const f16x8*)(aB + (m * 16 + rrow) * 128 + (kb ^ rd_sw)); \
                _Pragma("unroll")                                                  \
                for (int n = 0; n < 4; ++n)                                        \
                    acc[m][n] = __builtin_amdgcn_mfma_f32_16x16x32_f16(            \
                        af, BRD[ks * 4 + n], acc[m][n], 0, 0, 0);                  \
            }                                                                      \
            __builtin_amdgcn_s_setprio(0);                                         \
        }                                                                          \
        {                                                                          \
            const int stg = (rd >= 1) ? rd - 1 : 2;        /* (rd+2)%3 */          \
            const int t2  = ((T) + 2 < NT) ? (T) + 2 : NT - 1;                     \
            STAGE_A(&As[stg][0], t2 * 64);                                         \
        }                                                                          \
        rd = (rd < 2) ? rd + 1 : 0;                                                \
    }

    for (int t = 0; t < NT; t += 2) {
        ITER(t,     BR0, BR1);
        ITER(t + 1, BR1, BR0);
    }
#undef ITER
#undef LOADB
#undef STAGE_A

    // epilogue: C/D col=lane&15, row=(lane>>4)*4+r (m89-verified)
    #pragma unroll
    for (int n = 0; n < 4; ++n) {
        const int col = bn0 + wn0 + n * 16 + (lane & 15);
        const float b_f = bias[col];
        #pragma unroll
        for (int m = 0; m < 8; ++m) {
            const int row_base = bm0 + m * 16 + ((lane >> 4) << 2);
            #pragma unroll
            for (int r = 0; r < 4; ++r) {
                const int row = row_base + r;
                if (row < M)
                    out[(size_t)row * N_DIM + col] = acc[m][n][r] + b_f;
            }
        }
    }
}

// ---- fallback: fused kernel (proven rounds 6-8) ----
template <bool XF16>
__global__ __launch_bounds__(256, 2)
void awq_gemm_fused(const void* __restrict__ xin,
                    const int* __restrict__ qw,
                    const int* __restrict__ qz,
                    const float* __restrict__ sc,
                    const float* __restrict__ bias,
                    float* __restrict__ out,
                    int M)
{
    __shared__ __align__(16) _Float16 Asf[BM * ASTR];
    __shared__ __align__(16) int Wq[32 * WSTR];

    const int tid  = threadIdx.x;
    const int lane = tid & 63;
    const int wid  = tid >> 6;
    const int bn0 = blockIdx.x * BN;
    const int bm0 = blockIdx.y * BM;
    const int w0  = bn0 >> 3;
    const int wn0 = wid * 64;
    const int a_row = tid >> 3;
    const int a_col = (tid & 7) * 8;
    const int b_krow = tid >> 2;
    const int b_wg   = (tid & 3) * 4;

    int n_loc[4], w_loc[4], shf[4];
    #pragma unroll
    for (int bn = 0; bn < 4; ++bn) {
        n_loc[bn] = wn0 + bn * 16 + (lane & 15);
        w_loc[bn] = n_loc[bn] >> 3;
        int j = n_loc[bn] & 7;
        shf[bn] = ((j & 1) << 4) + ((j >> 1) << 2);
    }
    f16x2 s2[4], c2[4];
    f32x4 acc[8][4];
    #pragma unroll
    for (int i = 0; i < 8; ++i)
        #pragma unroll
        for (int j = 0; j < 4; ++j)
            acc[i][j] = (f32x4){0.f, 0.f, 0.f, 0.f};
    int4v aReg16[4];
    f32x8 aReg32[4];
    int4v bReg[2];
    const ushort* x16 = (const ushort*)xin;
    const float*  x32 = (const float*)xin;

#define LOAD_TILE(K0)                                                                  \
    {                                                                                  \
        _Pragma("unroll")                                                              \
        for (int i = 0; i < 4; ++i) {                                                  \
            int row = bm0 + a_row + i * 32;                                            \
            if constexpr (XF16) {                                                      \
                if (row < M)                                                           \
                    aReg16[i] = *(const int4v*)(x16 + (size_t)row * K_DIM + (K0) + a_col); \
                else aReg16[i] = (int4v){0, 0, 0, 0};                                  \
            } else {                                                                   \
                if (row < M)                                                           \
                    aReg32[i] = *(const f32x8*)(x32 + (size_t)row * K_DIM + (K0) + a_col); \
                else aReg32[i] = (f32x8){0.f,0.f,0.f,0.f,0.f,0.f,0.f,0.f};             \
            }                                                                          \
        }                                                                              \
        bReg[0] = *(const int4v*)(qw + (size_t)((K0) + b_krow) * WORDS_N + w0 + b_wg);      \
        bReg[1] = *(const int4v*)(qw + (size_t)((K0) + b_krow) * WORDS_N + w0 + b_wg + 16); \
    }

    LOAD_TILE(0);
    const int NT = K_DIM / BK;
    for (int t = 0; t < NT; ++t) {
        const int k0 = t * BK;
        __syncthreads();
        #pragma unroll
        for (int i = 0; i < 4; ++i) {
            if constexpr (XF16) {
                *(int4v*)&Asf[(a_row + i * 32) * ASTR + a_col] = aReg16[i];
            } else {
                f16x8 hh2;
                #pragma unroll
                for (int r = 0; r < 4; ++r) {
                    f16x2 p = __builtin_bit_cast(f16x2,
                        __builtin_amdgcn_cvt_pkrtz(aReg32[i][2*r], aReg32[i][2*r+1]));
                    hh2[2*r] = p[0]; hh2[2*r+1] = p[1];
                }
                *(f16x8*)&Asf[(a_row + i * 32) * ASTR + a_col] = hh2;
            }
        }
        #pragma unroll
        for (int c = 0; c < 4; ++c) {
            Wq[(b_wg + c) * WSTR + b_krow]      = bReg[0][c];
            Wq[(b_wg + 16 + c) * WSTR + b_krow] = bReg[1][c];
        }
        __syncthreads();
        if (t + 1 < NT) LOAD_TILE(k0 + BK);
        if ((t & 1) == 0) {
            const int gg = k0 >> 7;
            #pragma unroll
            for (int bn = 0; bn < 4; ++bn) {
                float s = sc[(size_t)gg * N_DIM + bn0 + n_loc[bn]];
                int zq  = (qz[(size_t)gg * WORDS_N + w0 + w_loc[bn]] >> shf[bn]) & 0xF;
                _Float16 sh = (_Float16)s;
                _Float16 nz = (_Float16)(-(float)zq * s);
                s2[bn] = (f16x2){sh, sh};
                c2[bn] = (f16x2){nz, nz};
            }
        }
        #pragma unroll
        for (int ks = 0; ks < 2; ++ks) {
            const int kk = ks * 32 + (lane >> 4) * 8;
            f16x8 af[8];
            #pragma unroll
            for (int am = 0; am < 8; ++am)
                af[am] = *(const f16x8*)&Asf[(am * 16 + (lane & 15)) * ASTR + kk];
            #pragma unroll
            for (int bn = 0; bn < 4; ++bn) {
                const int4v lo = *(const int4v*)&Wq[w_loc[bn] * WSTR + kk];
                const int4v hi = *(const int4v*)&Wq[w_loc[bn] * WSTR + kk + 4];
                f16x8 bfr;
                f16x2 p;
                p = dq2(lo[0], lo[1], shf[bn], s2[bn], c2[bn]); bfr[0]=p[0]; bfr[1]=p[1];
                p = dq2(lo[2], lo[3], shf[bn], s2[bn], c2[bn]); bfr[2]=p[0]; bfr[3]=p[1];
                p = dq2(hi[0], hi[1], shf[bn], s2[bn], c2[bn]); bfr[4]=p[0]; bfr[5]=p[1];
                p = dq2(hi[2], hi[3], shf[bn], s2[bn], c2[bn]); bfr[6]=p[0]; bfr[7]=p[1];
                #pragma unroll
                for (int am = 0; am < 8; ++am)
                    acc[am][bn] = __builtin_amdgcn_mfma_f32_16x16x32_f16(
                        af[am], bfr, acc[am][bn], 0, 0, 0);
            }
        }
    }
    #pragma unroll
    for (int bn = 0; bn < 4; ++bn) {
        const int col = bn0 + wn0 + bn * 16 + (lane & 15);
        const float b_f = bias[col];
        #pragma unroll
        for (int am = 0; am < 8; ++am) {
            const int row_base = bm0 + am * 16 + ((lane >> 4) << 2);
            #pragma unroll
            for (int r = 0; r < 4; ++r) {
                const int row = row_base + r;
                if (row < M)
                    out[(size_t)row * N_DIM + col] = acc[am][bn][r] + b_f;
            }
        }
    }
#undef LOAD_TILE
}

extern "C" void kernel_launch(void* const* d_in, const int* in_sizes, int n_in,
                              void* d_out, int out_size, void* d_ws, size_t ws_size,
                              hipStream_t stream) {
    const float* x    = (const float*)d_in[0];
    const int*   qw   = (const int*)d_in[1];
    const int*   qz   = (const int*)d_in[2];
    const float* sc   = (const float*)d_in[3];
    const float* bias = (const float*)d_in[4];
    float*       out  = (float*)d_out;

    const int M = in_sizes[0] / K_DIM;
    const size_t x_bytes = (size_t)M * K_DIM * 2;
    const size_t w_bytes = (size_t)N_DIM * K_DIM * 2;

    if (ws_size >= x_bytes + w_bytes && (M % 128) == 0) {
        ushort* xf = (ushort*)d_ws;
        f16x8*  Wf = (f16x8*)((char*)d_ws + x_bytes);
        cvt_x_kernel<<<dim3(2048), dim3(256), 0, stream>>>(x, xf, (M * K_DIM) / 8);
        dequant_w_kernel<<<dim3(WORDS_N / 8, K_DIM / 64), dim3(256), 0, stream>>>(qw, qz, sc, Wf);
        const int nwg = (N_DIM / 256) * (M / 128);   // 43 x 16 = 688, %8==0
        awq_gemm_pipe<<<dim3(nwg), dim3(256), 0, stream>>>(xf, Wf, bias, out, M, nwg);
    } else if (ws_size >= x_bytes) {
        ushort* xf = (ushort*)d_ws;
        const int mtiles = (M + BM - 1) / BM;
        cvt_x_kernel<<<dim3(2048), dim3(256), 0, stream>>>(x, xf, (M * K_DIM) / 8);
        awq_gemm_fused<true><<<dim3(N_DIM / BN, mtiles), dim3(256), 0, stream>>>(
            xf, qw, qz, sc, bias, out, M);
    } else {
        const int mtiles = (M + BM - 1) / BM;
        awq_gemm_fused<false><<<dim3(N_DIM / BN, mtiles), dim3(256), 0, stream>>>(
            x, qw, qz, sc, bias, out, M);
    }
}

// Round 20
// 238.598 us; speedup vs baseline: 1.0320x; 1.0162x over previous
//
#include <hip/hip_runtime.h>
#include <stdint.h>

#define K_DIM 4096
#define N_DIM 11008
#define WORDS_N 1376          // N_DIM / 8 packed words
#define BM 128
#define BN 256
#define BK 64
#define ASTR 72               // fused-fallback As stride
#define WSTR 68               // Wq stride (ints)

typedef _Float16 f16x2 __attribute__((ext_vector_type(2)));
typedef _Float16 f16x8 __attribute__((ext_vector_type(8)));
typedef float    f32x4 __attribute__((ext_vector_type(4)));
typedef float    f32x8 __attribute__((ext_vector_type(8)));
typedef int      int4v __attribute__((ext_vector_type(4)));
typedef int      int2v __attribute__((ext_vector_type(2)));
typedef unsigned short ushort;
typedef unsigned int u32;

__device__ __forceinline__ f16x2 dq2(int wa, int wb, int shf, f16x2 s2, f16x2 c2) {
    u32 t0 = ((u32)wa >> shf) & 0xFu;
    u32 t1 = ((u32)wb >> shf) & 0xFu;
    u32 h  = 0x64006400u | t0 | (t1 << 16);
    f16x2 q = __builtin_bit_cast(f16x2, h);
    q = q - (f16x2)((_Float16)1024.0f);
    return q * s2 + c2;
}

__device__ __forceinline__ void gload16(const void* g, void* l) {
    __builtin_amdgcn_global_load_lds(
        (const __attribute__((address_space(1))) unsigned int*)g,
        (__attribute__((address_space(3))) unsigned int*)l, 16, 0, 0);
}

// ---- pre-pass 1: x f32 -> fp16 ----
__global__ __launch_bounds__(256)
void cvt_x_kernel(const float* __restrict__ x, ushort* __restrict__ xf, int n8) {
    for (int i = blockIdx.x * 256 + threadIdx.x; i < n8; i += gridDim.x * 256) {
        f32x4 a = *(const f32x4*)(x + (size_t)i * 8);
        f32x4 b = *(const f32x4*)(x + (size_t)i * 8 + 4);
        int4v o;
        o[0] = __builtin_bit_cast(int, __builtin_amdgcn_cvt_pkrtz(a[0], a[1]));
        o[1] = __builtin_bit_cast(int, __builtin_amdgcn_cvt_pkrtz(a[2], a[3]));
        o[2] = __builtin_bit_cast(int, __builtin_amdgcn_cvt_pkrtz(b[0], b[1]));
        o[3] = __builtin_bit_cast(int, __builtin_amdgcn_cvt_pkrtz(b[2], b[3]));
        *(int4v*)(xf + (size_t)i * 8) = o;
    }
}

// ---- pre-pass 2: dequant qweight -> W in MFMA-fragment order ----
// unit = f16x8. unit_idx = (ntile*512 + kidx)*16 + (col&15)
__global__ __launch_bounds__(256)
void dequant_w_kernel(const int* __restrict__ qw,
                      const int* __restrict__ qz,
                      const float* __restrict__ sc,
                      f16x8* __restrict__ Wf)
{
    __shared__ __align__(16) int Wq[8 * WSTR];
    const int t  = threadIdx.x;
    const int w0 = blockIdx.x * 8;
    const int n0 = blockIdx.x * 64;
    const int k0 = blockIdx.y * 64;
    {
        const int k  = t >> 2;
        const int wp = (t & 3) * 2;
        const int2v v = *(const int2v*)(qw + (size_t)(k0 + k) * WORDS_N + w0 + wp);
        Wq[(wp + 0) * WSTR + k] = v[0];
        Wq[(wp + 1) * WSTR + k] = v[1];
    }
    __syncthreads();

    const int n   = t & 63;
    const int oc0 = t >> 6;
    const int w   = n >> 3;
    const int j   = n & 7;
    const int shf = ((j & 1) << 4) + ((j >> 1) << 2);
    const int g   = k0 >> 7;

    const int   nn = n0 + n;
    const float s  = sc[(size_t)g * N_DIM + nn];
    const int   zq = (qz[(size_t)g * WORDS_N + w0 + w] >> shf) & 0xF;
    const float nz = -(float)zq * s;

    #pragma unroll
    for (int oo = 0; oo < 2; ++oo) {
        const int oc = oc0 + oo * 4;
        const int4v lo = *(const int4v*)&Wq[w * WSTR + oc * 8];
        const int4v hi = *(const int4v*)&Wq[w * WSTR + oc * 8 + 4];
        f16x8 h;
        #pragma unroll
        for (int r = 0; r < 4; ++r)
            h[r] = (_Float16)((float)((lo[r] >> shf) & 0xF) * s + nz);
        #pragma unroll
        for (int r = 0; r < 4; ++r)
            h[4 + r] = (_Float16)((float)((hi[r] >> shf) & 0xF) * s + nz);
        const size_t kidx = (size_t)((k0 >> 3) + oc);
        Wf[((size_t)(nn >> 4) * 512 + kidx) * 16 + (nn & 15)] = h;
    }
}

// ---- main GEMM (rounds 14/17/19 structure, setprio REMOVED per m190):
//      128M x 256N block, 4 waves each owning 128x64 (acc[8][4]). Tri-buffered
//      A (gload_lds+swizzle), ONE barrier + counted vmcnt(12) per K-tile,
//      B double-buffered in regs from fragment-ordered Wf. 2 blocks/CU. ----
__global__ __launch_bounds__(256, 2)
void awq_gemm_pipe(const ushort* __restrict__ x16,
                   const f16x8* __restrict__ Wf,
                   const float* __restrict__ bias,
                   float* __restrict__ out,
                   int M, int nwg)
{
    __shared__ __align__(16) _Float16 As[3][128 * 64];  // 3 x 16 KB, A only

    const int tid  = threadIdx.x;
    const int lane = tid & 63;
    const int wid  = tid >> 6;

    // XCD swizzle: nwg divisible by 8; consecutive logical g share bx (B panel).
    const int hh  = blockIdx.x;
    const int g   = (hh & 7) * (nwg >> 3) + (hh >> 3);
    const int bx  = g >> 4;          // N tile (0..42)
    const int by  = g & 15;          // M tile (0..15)
    const int bn0 = bx * 256;
    const int bm0 = by * 128;

    const int wn0 = wid * 64;        // wave owns all 128 rows x 64 distinct cols

    // A staging: linear LDS dest, pre-swizzled global slot (proven round 10)
    const int srow = lane >> 3;
    const int slot = (lane & 7) ^ srow;
    const ushort* aSrc = x16 + (size_t)(bm0 + wid * 32 + srow) * K_DIM + slot * 8;

#define STAGE_A(BUFP, K0)                                                       \
    {                                                                           \
        _Pragma("unroll")                                                       \
        for (int jj = 0; jj < 4; ++jj)                                          \
            gload16(aSrc + (size_t)(K0) + jj * 8 * K_DIM,                       \
                    (BUFP) + (wid * 32 + jj * 8) * 64);                         \
    }

    // B fragment bases: unit idx = ntile*8192 + T*128 + ks*64 + lane
    size_t nb[4];
    #pragma unroll
    for (int n = 0; n < 4; ++n)
        nb[n] = ((size_t)((bn0 + wn0) >> 4) + n) * 8192 + lane;

    f32x4 acc[8][4];
    #pragma unroll
    for (int i = 0; i < 8; ++i)
        #pragma unroll
        for (int j = 0; j < 4; ++j)
            acc[i][j] = (f32x4){0.f, 0.f, 0.f, 0.f};

    f16x8 BR0[8], BR1[8];
    const int NT = K_DIM / 64;  // 64

#define LOADB(DST, T)                                                           \
    {                                                                           \
        const size_t koff = (size_t)(T) * 128;                                  \
        _Pragma("unroll")                                                       \
        for (int jj = 0; jj < 8; ++jj)                                          \
            DST[jj] = Wf[nb[jj & 3] + koff + (size_t)(jj >> 2) * 64];           \
    }

    const int rd_sw = (lane & 7) << 4;
    const int rrow  = lane & 15;

    // prologue: A0 -> buf0, B0 -> regs, A1 -> buf1 (issue order = vmcnt order)
    STAGE_A(&As[0][0], 0);
    LOADB(BR0, 0);
    STAGE_A(&As[1][0], 64);

    int rd = 0;   // buffer holding tile T (cycles 0,1,2)

    // ONE barrier per K-tile. STAGE at end of iter T writes buf[(rd+2)%3],
    // last read in iter T-1 (its readers passed this iter's top barrier).
    // In flight at top of T: B(T)8 + A(T+1)4 newer than A(T) -> vmcnt(12).
    // NOTE: no s_setprio — m190: setprio regresses barrier-synced lockstep GEMM.
#define ITER(T, BRD, BWR)                                                          \
    {                                                                              \
        asm volatile("s_waitcnt vmcnt(12)" ::: "memory");                          \
        __builtin_amdgcn_sched_barrier(0);                                         \
        __builtin_amdgcn_s_barrier();                                              \
        __builtin_amdgcn_sched_barrier(0);                                         \
        { const int tn = ((T) + 1 < NT) ? (T) + 1 : NT - 1; LOADB(BWR, tn); }      \
        __builtin_amdgcn_sched_barrier(0);                                         \
        const char* aB = (const char*)&As[rd][0];                                  \
        _Pragma("unroll")                                                          \
        for (int ks = 0; ks < 2; ++ks) {                                           \
            const int kb = ks * 64 + ((lane >> 4) << 4);                           \
            _Pragma("unroll")                                                      \
            for (int m = 0; m < 8; ++m) {                                          \
                f16x8 af = *(const f16x8*)(aB + (m * 16 + rrow) * 128 + (kb ^ rd_sw)); \
                _Pragma("unroll")                                                  \
                for (int n = 0; n < 4; ++n)                                        \
                    acc[m][n] = __builtin_amdgcn_mfma_f32_16x16x32_f16(            \
                        af, BRD[ks * 4 + n], acc[m][n], 0, 0, 0);                  \
            }                                                                      \
        }                                                                          \
        {                                                                          \
            const int stg = (rd >= 1) ? rd - 1 : 2;        /* (rd+2)%3 */          \
            const int t2  = ((T) + 2 < NT) ? (T) + 2 : NT - 1;                     \
            STAGE_A(&As[stg][0], t2 * 64);                                         \
        }                                                                          \
        rd = (rd < 2) ? rd + 1 : 0;                                                \
    }

    for (int t = 0; t < NT; t += 2) {
        ITER(t,     BR0, BR1);
        ITER(t + 1, BR1, BR0);
    }
#undef ITER
#undef LOADB
#undef STAGE_A

    // epilogue: C/D col=lane&15, row=(lane>>4)*4+r (m89-verified)
    #pragma unroll
    for (int n = 0; n < 4; ++n) {
        const int col = bn0 + wn0 + n * 16 + (lane & 15);
        const float b_f = bias[col];
        #pragma unroll
        for (int m = 0; m < 8; ++m) {
            const int row_base = bm0 + m * 16 + ((lane >> 4) << 2);
            #pragma unroll
            for (int r = 0; r < 4; ++r) {
                const int row = row_base + r;
                if (row < M)
                    out[(size_t)row * N_DIM + col] = acc[m][n][r] + b_f;
            }
        }
    }
}

// ---- fallback: fused kernel (proven rounds 6-8) ----
template <bool XF16>
__global__ __launch_bounds__(256, 2)
void awq_gemm_fused(const void* __restrict__ xin,
                    const int* __restrict__ qw,
                    const int* __restrict__ qz,
                    const float* __restrict__ sc,
                    const float* __restrict__ bias,
                    float* __restrict__ out,
                    int M)
{
    __shared__ __align__(16) _Float16 Asf[BM * ASTR];
    __shared__ __align__(16) int Wq[32 * WSTR];

    const int tid  = threadIdx.x;
    const int lane = tid & 63;
    const int wid  = tid >> 6;
    const int bn0 = blockIdx.x * BN;
    const int bm0 = blockIdx.y * BM;
    const int w0  = bn0 >> 3;
    const int wn0 = wid * 64;
    const int a_row = tid >> 3;
    const int a_col = (tid & 7) * 8;
    const int b_krow = tid >> 2;
    const int b_wg   = (tid & 3) * 4;

    int n_loc[4], w_loc[4], shf[4];
    #pragma unroll
    for (int bn = 0; bn < 4; ++bn) {
        n_loc[bn] = wn0 + bn * 16 + (lane & 15);
        w_loc[bn] = n_loc[bn] >> 3;
        int j = n_loc[bn] & 7;
        shf[bn] = ((j & 1) << 4) + ((j >> 1) << 2);
    }
    f16x2 s2[4], c2[4];
    f32x4 acc[8][4];
    #pragma unroll
    for (int i = 0; i < 8; ++i)
        #pragma unroll
        for (int j = 0; j < 4; ++j)
            acc[i][j] = (f32x4){0.f, 0.f, 0.f, 0.f};
    int4v aReg16[4];
    f32x8 aReg32[4];
    int4v bReg[2];
    const ushort* x16 = (const ushort*)xin;
    const float*  x32 = (const float*)xin;

#define LOAD_TILE(K0)                                                                  \
    {                                                                                  \
        _Pragma("unroll")                                                              \
        for (int i = 0; i < 4; ++i) {                                                  \
            int row = bm0 + a_row + i * 32;                                            \
            if constexpr (XF16) {                                                      \
                if (row < M)                                                           \
                    aReg16[i] = *(const int4v*)(x16 + (size_t)row * K_DIM + (K0) + a_col); \
                else aReg16[i] = (int4v){0, 0, 0, 0};                                  \
            } else {                                                                   \
                if (row < M)                                                           \
                    aReg32[i] = *(const f32x8*)(x32 + (size_t)row * K_DIM + (K0) + a_col); \
                else aReg32[i] = (f32x8){0.f,0.f,0.f,0.f,0.f,0.f,0.f,0.f};             \
            }                                                                          \
        }                                                                              \
        bReg[0] = *(const int4v*)(qw + (size_t)((K0) + b_krow) * WORDS_N + w0 + b_wg);      \
        bReg[1] = *(const int4v*)(qw + (size_t)((K0) + b_krow) * WORDS_N + w0 + b_wg + 16); \
    }

    LOAD_TILE(0);
    const int NT = K_DIM / BK;
    for (int t = 0; t < NT; ++t) {
        const int k0 = t * BK;
        __syncthreads();
        #pragma unroll
        for (int i = 0; i < 4; ++i) {
            if constexpr (XF16) {
                *(int4v*)&Asf[(a_row + i * 32) * ASTR + a_col] = aReg16[i];
            } else {
                f16x8 hh2;
                #pragma unroll
                for (int r = 0; r < 4; ++r) {
                    f16x2 p = __builtin_bit_cast(f16x2,
                        __builtin_amdgcn_cvt_pkrtz(aReg32[i][2*r], aReg32[i][2*r+1]));
                    hh2[2*r] = p[0]; hh2[2*r+1] = p[1];
                }
                *(f16x8*)&Asf[(a_row + i * 32) * ASTR + a_col] = hh2;
            }
        }
        #pragma unroll
        for (int c = 0; c < 4; ++c) {
            Wq[(b_wg + c) * WSTR + b_krow]      = bReg[0][c];
            Wq[(b_wg + 16 + c) * WSTR + b_krow] = bReg[1][c];
        }
        __syncthreads();
        if (t + 1 < NT) LOAD_TILE(k0 + BK);
        if ((t & 1) == 0) {
            const int gg = k0 >> 7;
            #pragma unroll
            for (int bn = 0; bn < 4; ++bn) {
                float s = sc[(size_t)gg * N_DIM + bn0 + n_loc[bn]];
                int zq  = (qz[(size_t)gg * WORDS_N + w0 + w_loc[bn]] >> shf[bn]) & 0xF;
                _Float16 sh = (_Float16)s;
                _Float16 nz = (_Float16)(-(float)zq * s);
                s2[bn] = (f16x2){sh, sh};
                c2[bn] = (f16x2){nz, nz};
            }
        }
        #pragma unroll
        for (int ks = 0; ks < 2; ++ks) {
            const int kk = ks * 32 + (lane >> 4) * 8;
            f16x8 af[8];
            #pragma unroll
            for (int am = 0; am < 8; ++am)
                af[am] = *(const f16x8*)&Asf[(am * 16 + (lane & 15)) * ASTR + kk];
            #pragma unroll
            for (int bn = 0; bn < 4; ++bn) {
                const int4v lo = *(const int4v*)&Wq[w_loc[bn] * WSTR + kk];
                const int4v hi = *(const int4v*)&Wq[w_loc[bn] * WSTR + kk + 4];
                f16x8 bfr;
                f16x2 p;
                p = dq2(lo[0], lo[1], shf[bn], s2[bn], c2[bn]); bfr[0]=p[0]; bfr[1]=p[1];
                p = dq2(lo[2], lo[3], shf[bn], s2[bn], c2[bn]); bfr[2]=p[0]; bfr[3]=p[1];
                p = dq2(hi[0], hi[1], shf[bn], s2[bn], c2[bn]); bfr[4]=p[0]; bfr[5]=p[1];
                p = dq2(hi[2], hi[3], shf[bn], s2[bn], c2[bn]); bfr[6]=p[0]; bfr[7]=p[1];
                #pragma unroll
                for (int am = 0; am < 8; ++am)
                    acc[am][bn] = __builtin_amdgcn_mfma_f32_16x16x32_f16(
                        af[am], bfr, acc[am][bn], 0, 0, 0);
            }
        }
    }
    #pragma unroll
    for (int bn = 0; bn < 4; ++bn) {
        const int col = bn0 + wn0 + bn * 16 + (lane & 15);
        const float b_f = bias[col];
        #pragma unroll
        for (int am = 0; am < 8; ++am) {
            const int row_base = bm0 + am * 16 + ((lane >> 4) << 2);
            #pragma unroll
            for (int r = 0; r < 4; ++r) {
                const int row = row_base + r;
                if (row < M)
                    out[(size_t)row * N_DIM + col] = acc[am][bn][r] + b_f;
            }
        }
    }
#undef LOAD_TILE
}

extern "C" void kernel_launch(void* const* d_in, const int* in_sizes, int n_in,
                              void* d_out, int out_size, void* d_ws, size_t ws_size,
                              hipStream_t stream) {
    const float* x    = (const float*)d_in[0];
    const int*   qw   = (const int*)d_in[1];
    const int*   qz   = (const int*)d_in[2];
    const float* sc   = (const float*)d_in[3];
    const float* bias = (const float*)d_in[4];
    float*       out  = (float*)d_out;

    const int M = in_sizes[0] / K_DIM;
    const size_t x_bytes = (size_t)M * K_DIM * 2;
    const size_t w_bytes = (size_t)N_DIM * K_DIM * 2;

    if (ws_size >= x_bytes + w_bytes && (M % 128) == 0) {
        ushort* xf = (ushort*)d_ws;
        f16x8*  Wf = (f16x8*)((char*)d_ws + x_bytes);
        cvt_x_kernel<<<dim3(2048), dim3(256), 0, stream>>>(x, xf, (M * K_DIM) / 8);
        dequant_w_kernel<<<dim3(WORDS_N / 8, K_DIM / 64), dim3(256), 0, stream>>>(qw, qz, sc, Wf);
        const int nwg = (N_DIM / 256) * (M / 128);   // 43 x 16 = 688, %8==0
        awq_gemm_pipe<<<dim3(nwg), dim3(256), 0, stream>>>(xf, Wf, bias, out, M, nwg);
    } else if (ws_size >= x_bytes) {
        ushort* xf = (ushort*)d_ws;
        const int mtiles = (M + BM - 1) / BM;
        cvt_x_kernel<<<dim3(2048), dim3(256), 0, stream>>>(x, xf, (M * K_DIM) / 8);
        awq_gemm_fused<true><<<dim3(N_DIM / BN, mtiles), dim3(256), 0, stream>>>(
            xf, qw, qz, sc, bias, out, M);
    } else {
        const int mtiles = (M + BM - 1) / BM;
        awq_gemm_fused<false><<<dim3(N_DIM / BN, mtiles), dim3(256), 0, stream>>>(
            x, qw, qz, sc, bias, out, M);
    }
}

// Round 21
// 237.120 us; speedup vs baseline: 1.0384x; 1.0062x over previous
//
#include <hip/hip_runtime.h>
#include <stdint.h>

#define K_DIM 4096
#define N_DIM 11008
#define WORDS_N 1376          // N_DIM / 8 packed words
#define BM 128
#define BN 256
#define BK 64
#define ASTR 72               // fused-fallback As stride
#define WSTR 68               // Wq stride (ints)

typedef _Float16 f16x2 __attribute__((ext_vector_type(2)));
typedef _Float16 f16x8 __attribute__((ext_vector_type(8)));
typedef float    f32x4 __attribute__((ext_vector_type(4)));
typedef float    f32x8 __attribute__((ext_vector_type(8)));
typedef int      int4v __attribute__((ext_vector_type(4)));
typedef int      int2v __attribute__((ext_vector_type(2)));
typedef unsigned short ushort;
typedef unsigned int u32;

__device__ __forceinline__ f16x2 dq2(int wa, int wb, int shf, f16x2 s2, f16x2 c2) {
    u32 t0 = ((u32)wa >> shf) & 0xFu;
    u32 t1 = ((u32)wb >> shf) & 0xFu;
    u32 h  = 0x64006400u | t0 | (t1 << 16);
    f16x2 q = __builtin_bit_cast(f16x2, h);
    q = q - (f16x2)((_Float16)1024.0f);
    return q * s2 + c2;
}

__device__ __forceinline__ void gload16(const void* g, void* l) {
    __builtin_amdgcn_global_load_lds(
        (const __attribute__((address_space(1))) unsigned int*)g,
        (__attribute__((address_space(3))) unsigned int*)l, 16, 0, 0);
}

// ---- pre-pass 1: x f32 -> fp16 ----
__global__ __launch_bounds__(256)
void cvt_x_kernel(const float* __restrict__ x, ushort* __restrict__ xf, int n8) {
    for (int i = blockIdx.x * 256 + threadIdx.x; i < n8; i += gridDim.x * 256) {
        f32x4 a = *(const f32x4*)(x + (size_t)i * 8);
        f32x4 b = *(const f32x4*)(x + (size_t)i * 8 + 4);
        int4v o;
        o[0] = __builtin_bit_cast(int, __builtin_amdgcn_cvt_pkrtz(a[0], a[1]));
        o[1] = __builtin_bit_cast(int, __builtin_amdgcn_cvt_pkrtz(a[2], a[3]));
        o[2] = __builtin_bit_cast(int, __builtin_amdgcn_cvt_pkrtz(b[0], b[1]));
        o[3] = __builtin_bit_cast(int, __builtin_amdgcn_cvt_pkrtz(b[2], b[3]));
        *(int4v*)(xf + (size_t)i * 8) = o;
    }
}

// ---- pre-pass 2: dequant qweight -> W in MFMA-fragment order ----
// unit = f16x8. unit_idx = (ntile*512 + kidx)*16 + (col&15)
__global__ __launch_bounds__(256)
void dequant_w_kernel(const int* __restrict__ qw,
                      const int* __restrict__ qz,
                      const float* __restrict__ sc,
                      f16x8* __restrict__ Wf)
{
    __shared__ __align__(16) int Wq[8 * WSTR];
    const int t  = threadIdx.x;
    const int w0 = blockIdx.x * 8;
    const int n0 = blockIdx.x * 64;
    const int k0 = blockIdx.y * 64;
    {
        const int k  = t >> 2;
        const int wp = (t & 3) * 2;
        const int2v v = *(const int2v*)(qw + (size_t)(k0 + k) * WORDS_N + w0 + wp);
        Wq[(wp + 0) * WSTR + k] = v[0];
        Wq[(wp + 1) * WSTR + k] = v[1];
    }
    __syncthreads();

    const int n   = t & 63;
    const int oc0 = t >> 6;
    const int w   = n >> 3;
    const int j   = n & 7;
    const int shf = ((j & 1) << 4) + ((j >> 1) << 2);
    const int g   = k0 >> 7;

    const int   nn = n0 + n;
    const float s  = sc[(size_t)g * N_DIM + nn];
    const int   zq = (qz[(size_t)g * WORDS_N + w0 + w] >> shf) & 0xF;
    const float nz = -(float)zq * s;

    #pragma unroll
    for (int oo = 0; oo < 2; ++oo) {
        const int oc = oc0 + oo * 4;
        const int4v lo = *(const int4v*)&Wq[w * WSTR + oc * 8];
        const int4v hi = *(const int4v*)&Wq[w * WSTR + oc * 8 + 4];
        f16x8 h;
        #pragma unroll
        for (int r = 0; r < 4; ++r)
            h[r] = (_Float16)((float)((lo[r] >> shf) & 0xF) * s + nz);
        #pragma unroll
        for (int r = 0; r < 4; ++r)
            h[4 + r] = (_Float16)((float)((hi[r] >> shf) & 0xF) * s + nz);
        const size_t kidx = (size_t)((k0 >> 3) + oc);
        Wf[((size_t)(nn >> 4) * 512 + kidx) * 16 + (nn & 15)] = h;
    }
}

// ---- main GEMM (round-20 structure; LOADB sched_barrier removed per m141):
//      128M x 256N block, 4 waves each owning 128x64 (acc[8][4]). Tri-buffered
//      A (gload_lds+swizzle), ONE barrier + counted vmcnt(12) per K-tile,
//      B double-buffered in regs from fragment-ordered Wf. 2 blocks/CU.
//      No setprio (m190: regresses lockstep GEMM — verified −5% round 20). ----
__global__ __launch_bounds__(256, 2)
void awq_gemm_pipe(const ushort* __restrict__ x16,
                   const f16x8* __restrict__ Wf,
                   const float* __restrict__ bias,
                   float* __restrict__ out,
                   int M, int nwg)
{
    __shared__ __align__(16) _Float16 As[3][128 * 64];  // 3 x 16 KB, A only

    const int tid  = threadIdx.x;
    const int lane = tid & 63;
    const int wid  = tid >> 6;

    // XCD swizzle: nwg divisible by 8; consecutive logical g share bx (B panel).
    const int hh  = blockIdx.x;
    const int g   = (hh & 7) * (nwg >> 3) + (hh >> 3);
    const int bx  = g >> 4;          // N tile (0..42)
    const int by  = g & 15;          // M tile (0..15)
    const int bn0 = bx * 256;
    const int bm0 = by * 128;

    const int wn0 = wid * 64;        // wave owns all 128 rows x 64 distinct cols

    // A staging: linear LDS dest, pre-swizzled global slot (proven round 10)
    const int srow = lane >> 3;
    const int slot = (lane & 7) ^ srow;
    const ushort* aSrc = x16 + (size_t)(bm0 + wid * 32 + srow) * K_DIM + slot * 8;

#define STAGE_A(BUFP, K0)                                                       \
    {                                                                           \
        _Pragma("unroll")                                                       \
        for (int jj = 0; jj < 4; ++jj)                                          \
            gload16(aSrc + (size_t)(K0) + jj * 8 * K_DIM,                       \
                    (BUFP) + (wid * 32 + jj * 8) * 64);                         \
    }

    // B fragment bases: unit idx = ntile*8192 + T*128 + ks*64 + lane
    size_t nb[4];
    #pragma unroll
    for (int n = 0; n < 4; ++n)
        nb[n] = ((size_t)((bn0 + wn0) >> 4) + n) * 8192 + lane;

    f32x4 acc[8][4];
    #pragma unroll
    for (int i = 0; i < 8; ++i)
        #pragma unroll
        for (int j = 0; j < 4; ++j)
            acc[i][j] = (f32x4){0.f, 0.f, 0.f, 0.f};

    f16x8 BR0[8], BR1[8];
    const int NT = K_DIM / 64;  // 64

#define LOADB(DST, T)                                                           \
    {                                                                           \
        const size_t koff = (size_t)(T) * 128;                                  \
        _Pragma("unroll")                                                       \
        for (int jj = 0; jj < 8; ++jj)                                          \
            DST[jj] = Wf[nb[jj & 3] + koff + (size_t)(jj >> 2) * 64];           \
    }

    const int rd_sw = (lane & 7) << 4;
    const int rrow  = lane & 15;

    // prologue: A0 -> buf0, B0 -> regs, A1 -> buf1 (issue order = vmcnt order)
    STAGE_A(&As[0][0], 0);
    LOADB(BR0, 0);
    STAGE_A(&As[1][0], 64);

    int rd = 0;   // buffer holding tile T (cycles 0,1,2)

    // ONE barrier per K-tile. STAGE at end of iter T writes buf[(rd+2)%3],
    // last read in iter T-1 (its readers passed this iter's top barrier).
    // In flight at top of T: B(T)8 + A(T+1)4 newer than A(T) -> vmcnt(12).
    // sched_barrier after s_barrier is LOAD-BEARING (stops ds_read hoisting
    // above the barrier). No fence after LOADB: compiler may interleave the
    // B-load issue with ds_read/MFMA (count unaffected: 12 newer in any order).
#define ITER(T, BRD, BWR)                                                          \
    {                                                                              \
        asm volatile("s_waitcnt vmcnt(12)" ::: "memory");                          \
        __builtin_amdgcn_sched_barrier(0);                                         \
        __builtin_amdgcn_s_barrier();                                              \
        __builtin_amdgcn_sched_barrier(0);                                         \
        { const int tn = ((T) + 1 < NT) ? (T) + 1 : NT - 1; LOADB(BWR, tn); }      \
        const char* aB = (const char*)&As[rd][0];                                  \
        _Pragma("unroll")                                                          \
        for (int ks = 0; ks < 2; ++ks) {                                           \
            const int kb = ks * 64 + ((lane >> 4) << 4);                           \
            _Pragma("unroll")                                                      \
            for (int m = 0; m < 8; ++m) {                                          \
                f16x8 af = *(const f16x8*)(aB + (m * 16 + rrow) * 128 + (kb ^ rd_sw)); \
                _Pragma("unroll")                                                  \
                for (int n = 0; n < 4; ++n)                                        \
                    acc[m][n] = __builtin_amdgcn_mfma_f32_16x16x32_f16(            \
                        af, BRD[ks * 4 + n], acc[m][n], 0, 0, 0);                  \
            }                                                                      \
        }                                                                          \
        {                                                                          \
            const int stg = (rd >= 1) ? rd - 1 : 2;        /* (rd+2)%3 */          \
            const int t2  = ((T) + 2 < NT) ? (T) + 2 : NT - 1;                     \
            STAGE_A(&As[stg][0], t2 * 64);                                         \
        }                                                                          \
        rd = (rd < 2) ? rd + 1 : 0;                                                \
    }

    for (int t = 0; t < NT; t += 2) {
        ITER(t,     BR0, BR1);
        ITER(t + 1, BR1, BR0);
    }
#undef ITER
#undef LOADB
#undef STAGE_A

    // epilogue: C/D col=lane&15, row=(lane>>4)*4+r (m89-verified)
    #pragma unroll
    for (int n = 0; n < 4; ++n) {
        const int col = bn0 + wn0 + n * 16 + (lane & 15);
        const float b_f = bias[col];
        #pragma unroll
        for (int m = 0; m < 8; ++m) {
            const int row_base = bm0 + m * 16 + ((lane >> 4) << 2);
            #pragma unroll
            for (int r = 0; r < 4; ++r) {
                const int row = row_base + r;
                if (row < M)
                    out[(size_t)row * N_DIM + col] = acc[m][n][r] + b_f;
            }
        }
    }
}

// ---- fallback: fused kernel (proven rounds 6-8) ----
template <bool XF16>
__global__ __launch_bounds__(256, 2)
void awq_gemm_fused(const void* __restrict__ xin,
                    const int* __restrict__ qw,
                    const int* __restrict__ qz,
                    const float* __restrict__ sc,
                    const float* __restrict__ bias,
                    float* __restrict__ out,
                    int M)
{
    __shared__ __align__(16) _Float16 Asf[BM * ASTR];
    __shared__ __align__(16) int Wq[32 * WSTR];

    const int tid  = threadIdx.x;
    const int lane = tid & 63;
    const int wid  = tid >> 6;
    const int bn0 = blockIdx.x * BN;
    const int bm0 = blockIdx.y * BM;
    const int w0  = bn0 >> 3;
    const int wn0 = wid * 64;
    const int a_row = tid >> 3;
    const int a_col = (tid & 7) * 8;
    const int b_krow = tid >> 2;
    const int b_wg   = (tid & 3) * 4;

    int n_loc[4], w_loc[4], shf[4];
    #pragma unroll
    for (int bn = 0; bn < 4; ++bn) {
        n_loc[bn] = wn0 + bn * 16 + (lane & 15);
        w_loc[bn] = n_loc[bn] >> 3;
        int j = n_loc[bn] & 7;
        shf[bn] = ((j & 1) << 4) + ((j >> 1) << 2);
    }
    f16x2 s2[4], c2[4];
    f32x4 acc[8][4];
    #pragma unroll
    for (int i = 0; i < 8; ++i)
        #pragma unroll
        for (int j = 0; j < 4; ++j)
            acc[i][j] = (f32x4){0.f, 0.f, 0.f, 0.f};
    int4v aReg16[4];
    f32x8 aReg32[4];
    int4v bReg[2];
    const ushort* x16 = (const ushort*)xin;
    const float*  x32 = (const float*)xin;

#define LOAD_TILE(K0)                                                                  \
    {                                                                                  \
        _Pragma("unroll")                                                              \
        for (int i = 0; i < 4; ++i) {                                                  \
            int row = bm0 + a_row + i * 32;                                            \
            if constexpr (XF16) {                                                      \
                if (row < M)                                                           \
                    aReg16[i] = *(const int4v*)(x16 + (size_t)row * K_DIM + (K0) + a_col); \
                else aReg16[i] = (int4v){0, 0, 0, 0};                                  \
            } else {                                                                   \
                if (row < M)                                                           \
                    aReg32[i] = *(const f32x8*)(x32 + (size_t)row * K_DIM + (K0) + a_col); \
                else aReg32[i] = (f32x8){0.f,0.f,0.f,0.f,0.f,0.f,0.f,0.f};             \
            }                                                                          \
        }                                                                              \
        bReg[0] = *(const int4v*)(qw + (size_t)((K0) + b_krow) * WORDS_N + w0 + b_wg);      \
        bReg[1] = *(const int4v*)(qw + (size_t)((K0) + b_krow) * WORDS_N + w0 + b_wg + 16); \
    }

    LOAD_TILE(0);
    const int NT = K_DIM / BK;
    for (int t = 0; t < NT; ++t) {
        const int k0 = t * BK;
        __syncthreads();
        #pragma unroll
        for (int i = 0; i < 4; ++i) {
            if constexpr (XF16) {
                *(int4v*)&Asf[(a_row + i * 32) * ASTR + a_col] = aReg16[i];
            } else {
                f16x8 hh2;
                #pragma unroll
                for (int r = 0; r < 4; ++r) {
                    f16x2 p = __builtin_bit_cast(f16x2,
                        __builtin_amdgcn_cvt_pkrtz(aReg32[i][2*r], aReg32[i][2*r+1]));
                    hh2[2*r] = p[0]; hh2[2*r+1] = p[1];
                }
                *(f16x8*)&Asf[(a_row + i * 32) * ASTR + a_col] = hh2;
            }
        }
        #pragma unroll
        for (int c = 0; c < 4; ++c) {
            Wq[(b_wg + c) * WSTR + b_krow]      = bReg[0][c];
            Wq[(b_wg + 16 + c) * WSTR + b_krow] = bReg[1][c];
        }
        __syncthreads();
        if (t + 1 < NT) LOAD_TILE(k0 + BK);
        if ((t & 1) == 0) {
            const int gg = k0 >> 7;
            #pragma unroll
            for (int bn = 0; bn < 4; ++bn) {
                float s = sc[(size_t)gg * N_DIM + bn0 + n_loc[bn]];
                int zq  = (qz[(size_t)gg * WORDS_N + w0 + w_loc[bn]] >> shf[bn]) & 0xF;
                _Float16 sh = (_Float16)s;
                _Float16 nz = (_Float16)(-(float)zq * s);
                s2[bn] = (f16x2){sh, sh};
                c2[bn] = (f16x2){nz, nz};
            }
        }
        #pragma unroll
        for (int ks = 0; ks < 2; ++ks) {
            const int kk = ks * 32 + (lane >> 4) * 8;
            f16x8 af[8];
            #pragma unroll
            for (int am = 0; am < 8; ++am)
                af[am] = *(const f16x8*)&Asf[(am * 16 + (lane & 15)) * ASTR + kk];
            #pragma unroll
            for (int bn = 0; bn < 4; ++bn) {
                const int4v lo = *(const int4v*)&Wq[w_loc[bn] * WSTR + kk];
                const int4v hi = *(const int4v*)&Wq[w_loc[bn] * WSTR + kk + 4];
                f16x8 bfr;
                f16x2 p;
                p = dq2(lo[0], lo[1], shf[bn], s2[bn], c2[bn]); bfr[0]=p[0]; bfr[1]=p[1];
                p = dq2(lo[2], lo[3], shf[bn], s2[bn], c2[bn]); bfr[2]=p[0]; bfr[3]=p[1];
                p = dq2(hi[0], hi[1], shf[bn], s2[bn], c2[bn]); bfr[4]=p[0]; bfr[5]=p[1];
                p = dq2(hi[2], hi[3], shf[bn], s2[bn], c2[bn]); bfr[6]=p[0]; bfr[7]=p[1];
                #pragma unroll
                for (int am = 0; am < 8; ++am)
                    acc[am][bn] = __builtin_amdgcn_mfma_f32_16x16x32_f16(
                        af[am], bfr, acc[am][bn], 0, 0, 0);
            }
        }
    }
    #pragma unroll
    for (int bn = 0; bn < 4; ++bn) {
        const int col = bn0 + wn0 + bn * 16 + (lane & 15);
        const float b_f = bias[col];
        #pragma unroll
        for (int am = 0; am < 8; ++am) {
            const int row_base = bm0 + am * 16 + ((lane >> 4) << 2);
            #pragma unroll
            for (int r = 0; r < 4; ++r) {
                const int row = row_base + r;
                if (row < M)
                    out[(size_t)row * N_DIM + col] = acc[am][bn][r] + b_f;
            }
        }
    }
#undef LOAD_TILE
}

extern "C" void kernel_launch(void* const* d_in, const int* in_sizes, int n_in,
                              void* d_out, int out_size, void* d_ws, size_t ws_size,
                              hipStream_t stream) {
    const float* x    = (const float*)d_in[0];
    const int*   qw   = (const int*)d_in[1];
    const int*   qz   = (const int*)d_in[2];
    const float* sc   = (const float*)d_in[3];
    const float* bias = (const float*)d_in[4];
    float*       out  = (float*)d_out;

    const int M = in_sizes[0] / K_DIM;
    const size_t x_bytes = (size_t)M * K_DIM * 2;
    const size_t w_bytes = (size_t)N_DIM * K_DIM * 2;

    if (ws_size >= x_bytes + w_bytes && (M % 128) == 0) {
        ushort* xf = (ushort*)d_ws;
        f16x8*  Wf = (f16x8*)((char*)d_ws + x_bytes);
        cvt_x_kernel<<<dim3(2048), dim3(256), 0, stream>>>(x, xf, (M * K_DIM) / 8);
        dequant_w_kernel<<<dim3(WORDS_N / 8, K_DIM / 64), dim3(256), 0, stream>>>(qw, qz, sc, Wf);
        const int nwg = (N_DIM / 256) * (M / 128);   // 43 x 16 = 688, %8==0
        awq_gemm_pipe<<<dim3(nwg), dim3(256), 0, stream>>>(xf, Wf, bias, out, M, nwg);
    } else if (ws_size >= x_bytes) {
        ushort* xf = (ushort*)d_ws;
        const int mtiles = (M + BM - 1) / BM;
        cvt_x_kernel<<<dim3(2048), dim3(256), 0, stream>>>(x, xf, (M * K_DIM) / 8);
        awq_gemm_fused<true><<<dim3(N_DIM / BN, mtiles), dim3(256), 0, stream>>>(
            xf, qw, qz, sc, bias, out, M);
    } else {
        const int mtiles = (M + BM - 1) / BM;
        awq_gemm_fused<false><<<dim3(N_DIM / BN, mtiles), dim3(256), 0, stream>>>(
            x, qw, qz, sc, bias, out, M);
    }
}

// Round 22
// 236.206 us; speedup vs baseline: 1.0424x; 1.0039x over previous
//
#include <hip/hip_runtime.h>
#include <stdint.h>

#define K_DIM 4096
#define N_DIM 11008
#define WORDS_N 1376          // N_DIM / 8 packed words
#define BM 128
#define BN 256
#define BK 64
#define ASTR 72               // fused-fallback As stride
#define WSTR 68               // Wq stride (ints)

typedef _Float16 f16x2 __attribute__((ext_vector_type(2)));
typedef _Float16 f16x8 __attribute__((ext_vector_type(8)));
typedef float    f32x4 __attribute__((ext_vector_type(4)));
typedef float    f32x8 __attribute__((ext_vector_type(8)));
typedef int      int4v __attribute__((ext_vector_type(4)));
typedef int      int2v __attribute__((ext_vector_type(2)));
typedef unsigned short ushort;
typedef unsigned int u32;

__device__ __forceinline__ f16x2 dq2(int wa, int wb, int shf, f16x2 s2, f16x2 c2) {
    u32 t0 = ((u32)wa >> shf) & 0xFu;
    u32 t1 = ((u32)wb >> shf) & 0xFu;
    u32 h  = 0x64006400u | t0 | (t1 << 16);
    f16x2 q = __builtin_bit_cast(f16x2, h);
    q = q - (f16x2)((_Float16)1024.0f);
    return q * s2 + c2;
}

__device__ __forceinline__ void gload16(const void* g, void* l) {
    __builtin_amdgcn_global_load_lds(
        (const __attribute__((address_space(1))) unsigned int*)g,
        (__attribute__((address_space(3))) unsigned int*)l, 16, 0, 0);
}

// ---- pre-pass 1: x f32 -> fp16 ----
__global__ __launch_bounds__(256)
void cvt_x_kernel(const float* __restrict__ x, ushort* __restrict__ xf, int n8) {
    for (int i = blockIdx.x * 256 + threadIdx.x; i < n8; i += gridDim.x * 256) {
        f32x4 a = *(const f32x4*)(x + (size_t)i * 8);
        f32x4 b = *(const f32x4*)(x + (size_t)i * 8 + 4);
        int4v o;
        o[0] = __builtin_bit_cast(int, __builtin_amdgcn_cvt_pkrtz(a[0], a[1]));
        o[1] = __builtin_bit_cast(int, __builtin_amdgcn_cvt_pkrtz(a[2], a[3]));
        o[2] = __builtin_bit_cast(int, __builtin_amdgcn_cvt_pkrtz(b[0], b[1]));
        o[3] = __builtin_bit_cast(int, __builtin_amdgcn_cvt_pkrtz(b[2], b[3]));
        *(int4v*)(xf + (size_t)i * 8) = o;
    }
}

// ---- pre-pass 2: dequant qweight -> W in MFMA-fragment order ----
// unit = f16x8. unit_idx = (ntile*512 + kidx)*16 + (col&15)
__global__ __launch_bounds__(256)
void dequant_w_kernel(const int* __restrict__ qw,
                      const int* __restrict__ qz,
                      const float* __restrict__ sc,
                      f16x8* __restrict__ Wf)
{
    __shared__ __align__(16) int Wq[8 * WSTR];
    const int t  = threadIdx.x;
    const int w0 = blockIdx.x * 8;
    const int n0 = blockIdx.x * 64;
    const int k0 = blockIdx.y * 64;
    {
        const int k  = t >> 2;
        const int wp = (t & 3) * 2;
        const int2v v = *(const int2v*)(qw + (size_t)(k0 + k) * WORDS_N + w0 + wp);
        Wq[(wp + 0) * WSTR + k] = v[0];
        Wq[(wp + 1) * WSTR + k] = v[1];
    }
    __syncthreads();

    const int n   = t & 63;
    const int oc0 = t >> 6;
    const int w   = n >> 3;
    const int j   = n & 7;
    const int shf = ((j & 1) << 4) + ((j >> 1) << 2);
    const int g   = k0 >> 7;

    const int   nn = n0 + n;
    const float s  = sc[(size_t)g * N_DIM + nn];
    const int   zq = (qz[(size_t)g * WORDS_N + w0 + w] >> shf) & 0xF;
    const float nz = -(float)zq * s;

    #pragma unroll
    for (int oo = 0; oo < 2; ++oo) {
        const int oc = oc0 + oo * 4;
        const int4v lo = *(const int4v*)&Wq[w * WSTR + oc * 8];
        const int4v hi = *(const int4v*)&Wq[w * WSTR + oc * 8 + 4];
        f16x8 h;
        #pragma unroll
        for (int r = 0; r < 4; ++r)
            h[r] = (_Float16)((float)((lo[r] >> shf) & 0xF) * s + nz);
        #pragma unroll
        for (int r = 0; r < 4; ++r)
            h[4 + r] = (_Float16)((float)((hi[r] >> shf) & 0xF) * s + nz);
        const size_t kidx = (size_t)((k0 >> 3) + oc);
        Wf[((size_t)(nn >> 4) * 512 + kidx) * 16 + (nn & 15)] = h;
    }
}

// ---- main GEMM (round-21 structure; pre-barrier sched_barrier removed):
//      128M x 256N block, 4 waves each owning 128x64 (acc[8][4]). Tri-buffered
//      A (gload_lds+swizzle), ONE barrier + counted vmcnt(12) per K-tile,
//      B double-buffered in regs from fragment-ordered Wf. 2 blocks/CU.
//      No setprio (m190, −5% verified r20); no LOADB fence (m141, −3% r21). ----
__global__ __launch_bounds__(256, 2)
void awq_gemm_pipe(const ushort* __restrict__ x16,
                   const f16x8* __restrict__ Wf,
                   const float* __restrict__ bias,
                   float* __restrict__ out,
                   int M, int nwg)
{
    __shared__ __align__(16) _Float16 As[3][128 * 64];  // 3 x 16 KB, A only

    const int tid  = threadIdx.x;
    const int lane = tid & 63;
    const int wid  = tid >> 6;

    // XCD swizzle: nwg divisible by 8; consecutive logical g share bx (B panel).
    const int hh  = blockIdx.x;
    const int g   = (hh & 7) * (nwg >> 3) + (hh >> 3);
    const int bx  = g >> 4;          // N tile (0..42)
    const int by  = g & 15;          // M tile (0..15)
    const int bn0 = bx * 256;
    const int bm0 = by * 128;

    const int wn0 = wid * 64;        // wave owns all 128 rows x 64 distinct cols

    // A staging: linear LDS dest, pre-swizzled global slot (proven round 10)
    const int srow = lane >> 3;
    const int slot = (lane & 7) ^ srow;
    const ushort* aSrc = x16 + (size_t)(bm0 + wid * 32 + srow) * K_DIM + slot * 8;

#define STAGE_A(BUFP, K0)                                                       \
    {                                                                           \
        _Pragma("unroll")                                                       \
        for (int jj = 0; jj < 4; ++jj)                                          \
            gload16(aSrc + (size_t)(K0) + jj * 8 * K_DIM,                       \
                    (BUFP) + (wid * 32 + jj * 8) * 64);                         \
    }

    // B fragment bases: unit idx = ntile*8192 + T*128 + ks*64 + lane
    size_t nb[4];
    #pragma unroll
    for (int n = 0; n < 4; ++n)
        nb[n] = ((size_t)((bn0 + wn0) >> 4) + n) * 8192 + lane;

    f32x4 acc[8][4];
    #pragma unroll
    for (int i = 0; i < 8; ++i)
        #pragma unroll
        for (int j = 0; j < 4; ++j)
            acc[i][j] = (f32x4){0.f, 0.f, 0.f, 0.f};

    f16x8 BR0[8], BR1[8];
    const int NT = K_DIM / 64;  // 64

#define LOADB(DST, T)                                                           \
    {                                                                           \
        const size_t koff = (size_t)(T) * 128;                                  \
        _Pragma("unroll")                                                       \
        for (int jj = 0; jj < 8; ++jj)                                          \
            DST[jj] = Wf[nb[jj & 3] + koff + (size_t)(jj >> 2) * 64];           \
    }

    const int rd_sw = (lane & 7) << 4;
    const int rrow  = lane & 15;

    // prologue: A0 -> buf0, B0 -> regs, A1 -> buf1 (issue order = vmcnt order)
    STAGE_A(&As[0][0], 0);
    LOADB(BR0, 0);
    STAGE_A(&As[1][0], 64);

    int rd = 0;   // buffer holding tile T (cycles 0,1,2)

    // ONE barrier per K-tile. STAGE at end of iter T writes buf[(rd+2)%3],
    // last read in iter T-1 (its readers passed this iter's top barrier).
    // In flight at top of T: B(T)8 + A(T+1)4 newer than A(T) -> vmcnt(12).
    // Post-barrier sched_barrier is LOAD-BEARING (stops ds_read hoisting above
    // the barrier). Pre-barrier fence removed (nothing to order there; asm
    // "memory" clobber + barrier semantics pin vmcnt<->barrier order).
#define ITER(T, BRD, BWR)                                                          \
    {                                                                              \
        asm volatile("s_waitcnt vmcnt(12)" ::: "memory");                          \
        __builtin_amdgcn_s_barrier();                                              \
        __builtin_amdgcn_sched_barrier(0);                                         \
        { const int tn = ((T) + 1 < NT) ? (T) + 1 : NT - 1; LOADB(BWR, tn); }      \
        const char* aB = (const char*)&As[rd][0];                                  \
        _Pragma("unroll")                                                          \
        for (int ks = 0; ks < 2; ++ks) {                                           \
            const int kb = ks * 64 + ((lane >> 4) << 4);                           \
            _Pragma("unroll")                                                      \
            for (int m = 0; m < 8; ++m) {                                          \
                f16x8 af = *(const f16x8*)(aB + (m * 16 + rrow) * 128 + (kb ^ rd_sw)); \
                _Pragma("unroll")                                                  \
                for (int n = 0; n < 4; ++n)                                        \
                    acc[m][n] = __builtin_amdgcn_mfma_f32_16x16x32_f16(            \
                        af, BRD[ks * 4 + n], acc[m][n], 0, 0, 0);                  \
            }                                                                      \
        }                                                                          \
        {                                                                          \
            const int stg = (rd >= 1) ? rd - 1 : 2;        /* (rd+2)%3 */          \
            const int t2  = ((T) + 2 < NT) ? (T) + 2 : NT - 1;                     \
            STAGE_A(&As[stg][0], t2 * 64);                                         \
        }                                                                          \
        rd = (rd < 2) ? rd + 1 : 0;                                                \
    }

    for (int t = 0; t < NT; t += 2) {
        ITER(t,     BR0, BR1);
        ITER(t + 1, BR1, BR0);
    }
#undef ITER
#undef LOADB
#undef STAGE_A

    // epilogue: C/D col=lane&15, row=(lane>>4)*4+r (m89-verified)
    #pragma unroll
    for (int n = 0; n < 4; ++n) {
        const int col = bn0 + wn0 + n * 16 + (lane & 15);
        const float b_f = bias[col];
        #pragma unroll
        for (int m = 0; m < 8; ++m) {
            const int row_base = bm0 + m * 16 + ((lane >> 4) << 2);
            #pragma unroll
            for (int r = 0; r < 4; ++r) {
                const int row = row_base + r;
                if (row < M)
                    out[(size_t)row * N_DIM + col] = acc[m][n][r] + b_f;
            }
        }
    }
}

// ---- fallback: fused kernel (proven rounds 6-8) ----
template <bool XF16>
__global__ __launch_bounds__(256, 2)
void awq_gemm_fused(const void* __restrict__ xin,
                    const int* __restrict__ qw,
                    const int* __restrict__ qz,
                    const float* __restrict__ sc,
                    const float* __restrict__ bias,
                    float* __restrict__ out,
                    int M)
{
    __shared__ __align__(16) _Float16 Asf[BM * ASTR];
    __shared__ __align__(16) int Wq[32 * WSTR];

    const int tid  = threadIdx.x;
    const int lane = tid & 63;
    const int wid  = tid >> 6;
    const int bn0 = blockIdx.x * BN;
    const int bm0 = blockIdx.y * BM;
    const int w0  = bn0 >> 3;
    const int wn0 = wid * 64;
    const int a_row = tid >> 3;
    const int a_col = (tid & 7) * 8;
    const int b_krow = tid >> 2;
    const int b_wg   = (tid & 3) * 4;

    int n_loc[4], w_loc[4], shf[4];
    #pragma unroll
    for (int bn = 0; bn < 4; ++bn) {
        n_loc[bn] = wn0 + bn * 16 + (lane & 15);
        w_loc[bn] = n_loc[bn] >> 3;
        int j = n_loc[bn] & 7;
        shf[bn] = ((j & 1) << 4) + ((j >> 1) << 2);
    }
    f16x2 s2[4], c2[4];
    f32x4 acc[8][4];
    #pragma unroll
    for (int i = 0; i < 8; ++i)
        #pragma unroll
        for (int j = 0; j < 4; ++j)
            acc[i][j] = (f32x4){0.f, 0.f, 0.f, 0.f};
    int4v aReg16[4];
    f32x8 aReg32[4];
    int4v bReg[2];
    const ushort* x16 = (const ushort*)xin;
    const float*  x32 = (const float*)xin;

#define LOAD_TILE(K0)                                                                  \
    {                                                                                  \
        _Pragma("unroll")                                                              \
        for (int i = 0; i < 4; ++i) {                                                  \
            int row = bm0 + a_row + i * 32;                                            \
            if constexpr (XF16) {                                                      \
                if (row < M)                                                           \
                    aReg16[i] = *(const int4v*)(x16 + (size_t)row * K_DIM + (K0) + a_col); \
                else aReg16[i] = (int4v){0, 0, 0, 0};                                  \
            } else {                                                                   \
                if (row < M)                                                           \
                    aReg32[i] = *(const f32x8*)(x32 + (size_t)row * K_DIM + (K0) + a_col); \
                else aReg32[i] = (f32x8){0.f,0.f,0.f,0.f,0.f,0.f,0.f,0.f};             \
            }                                                                          \
        }                                                                              \
        bReg[0] = *(const int4v*)(qw + (size_t)((K0) + b_krow) * WORDS_N + w0 + b_wg);      \
        bReg[1] = *(const int4v*)(qw + (size_t)((K0) + b_krow) * WORDS_N + w0 + b_wg + 16); \
    }

    LOAD_TILE(0);
    const int NT = K_DIM / BK;
    for (int t = 0; t < NT; ++t) {
        const int k0 = t * BK;
        __syncthreads();
        #pragma unroll
        for (int i = 0; i < 4; ++i) {
            if constexpr (XF16) {
                *(int4v*)&Asf[(a_row + i * 32) * ASTR + a_col] = aReg16[i];
            } else {
                f16x8 hh2;
                #pragma unroll
                for (int r = 0; r < 4; ++r) {
                    f16x2 p = __builtin_bit_cast(f16x2,
                        __builtin_amdgcn_cvt_pkrtz(aReg32[i][2*r], aReg32[i][2*r+1]));
                    hh2[2*r] = p[0]; hh2[2*r+1] = p[1];
                }
                *(f16x8*)&Asf[(a_row + i * 32) * ASTR + a_col] = hh2;
            }
        }
        #pragma unroll
        for (int c = 0; c < 4; ++c) {
            Wq[(b_wg + c) * WSTR + b_krow]      = bReg[0][c];
            Wq[(b_wg + 16 + c) * WSTR + b_krow] = bReg[1][c];
        }
        __syncthreads();
        if (t + 1 < NT) LOAD_TILE(k0 + BK);
        if ((t & 1) == 0) {
            const int gg = k0 >> 7;
            #pragma unroll
            for (int bn = 0; bn < 4; ++bn) {
                float s = sc[(size_t)gg * N_DIM + bn0 + n_loc[bn]];
                int zq  = (qz[(size_t)gg * WORDS_N + w0 + w_loc[bn]] >> shf[bn]) & 0xF;
                _Float16 sh = (_Float16)s;
                _Float16 nz = (_Float16)(-(float)zq * s);
                s2[bn] = (f16x2){sh, sh};
                c2[bn] = (f16x2){nz, nz};
            }
        }
        #pragma unroll
        for (int ks = 0; ks < 2; ++ks) {
            const int kk = ks * 32 + (lane >> 4) * 8;
            f16x8 af[8];
            #pragma unroll
            for (int am = 0; am < 8; ++am)
                af[am] = *(const f16x8*)&Asf[(am * 16 + (lane & 15)) * ASTR + kk];
            #pragma unroll
            for (int bn = 0; bn < 4; ++bn) {
                const int4v lo = *(const int4v*)&Wq[w_loc[bn] * WSTR + kk];
                const int4v hi = *(const int4v*)&Wq[w_loc[bn] * WSTR + kk + 4];
                f16x8 bfr;
                f16x2 p;
                p = dq2(lo[0], lo[1], shf[bn], s2[bn], c2[bn]); bfr[0]=p[0]; bfr[1]=p[1];
                p = dq2(lo[2], lo[3], shf[bn], s2[bn], c2[bn]); bfr[2]=p[0]; bfr[3]=p[1];
                p = dq2(hi[0], hi[1], shf[bn], s2[bn], c2[bn]); bfr[4]=p[0]; bfr[5]=p[1];
                p = dq2(hi[2], hi[3], shf[bn], s2[bn], c2[bn]); bfr[6]=p[0]; bfr[7]=p[1];
                #pragma unroll
                for (int am = 0; am < 8; ++am)
                    acc[am][bn] = __builtin_amdgcn_mfma_f32_16x16x32_f16(
                        af[am], bfr, acc[am][bn], 0, 0, 0);
            }
        }
    }
    #pragma unroll
    for (int bn = 0; bn < 4; ++bn) {
        const int col = bn0 + wn0 + bn * 16 + (lane & 15);
        const float b_f = bias[col];
        #pragma unroll
        for (int am = 0; am < 8; ++am) {
            const int row_base = bm0 + am * 16 + ((lane >> 4) << 2);
            #pragma unroll
            for (int r = 0; r < 4; ++r) {
                const int row = row_base + r;
                if (row < M)
                    out[(size_t)row * N_DIM + col] = acc[am][bn][r] + b_f;
            }
        }
    }
#undef LOAD_TILE
}

extern "C" void kernel_launch(void* const* d_in, const int* in_sizes, int n_in,
                              void* d_out, int out_size, void* d_ws, size_t ws_size,
                              hipStream_t stream) {
    const float* x    = (const float*)d_in[0];
    const int*   qw   = (const int*)d_in[1];
    const int*   qz   = (const int*)d_in[2];
    const float* sc   = (const float*)d_in[3];
    const float* bias = (const float*)d_in[4];
    float*       out  = (float*)d_out;

    const int M = in_sizes[0] / K_DIM;
    const size_t x_bytes = (size_t)M * K_DIM * 2;
    const size_t w_bytes = (size_t)N_DIM * K_DIM * 2;

    if (ws_size >= x_bytes + w_bytes && (M % 128) == 0) {
        ushort* xf = (ushort*)d_ws;
        f16x8*  Wf = (f16x8*)((char*)d_ws + x_bytes);
        cvt_x_kernel<<<dim3(2048), dim3(256), 0, stream>>>(x, xf, (M * K_DIM) / 8);
        dequant_w_kernel<<<dim3(WORDS_N / 8, K_DIM / 64), dim3(256), 0, stream>>>(qw, qz, sc, Wf);
        const int nwg = (N_DIM / 256) * (M / 128);   // 43 x 16 = 688, %8==0
        awq_gemm_pipe<<<dim3(nwg), dim3(256), 0, stream>>>(xf, Wf, bias, out, M, nwg);
    } else if (ws_size >= x_bytes) {
        ushort* xf = (ushort*)d_ws;
        const int mtiles = (M + BM - 1) / BM;
        cvt_x_kernel<<<dim3(2048), dim3(256), 0, stream>>>(x, xf, (M * K_DIM) / 8);
        awq_gemm_fused<true><<<dim3(N_DIM / BN, mtiles), dim3(256), 0, stream>>>(
            xf, qw, qz, sc, bias, out, M);
    } else {
        const int mtiles = (M + BM - 1) / BM;
        awq_gemm_fused<false><<<dim3(N_DIM / BN, mtiles), dim3(256), 0, stream>>>(
            x, qw, qz, sc, bias, out, M);
    }
}